// Round 2
// baseline (85.262 us; speedup 1.0000x reference)
//
#include <hip/hip_runtime.h>
#include <stdint.h>

#define B_   2048
#define C_   1000
#define N2   4096
#define D_   256
#define JSPLIT 8

typedef float  f32x4  __attribute__((ext_vector_type(4)));
typedef short  short8 __attribute__((ext_vector_type(8)));

__device__ __forceinline__ float waveSum(float v){
#pragma unroll
  for (int o = 32; o; o >>= 1) v += __shfl_xor(v, o, 64);
  return v;
}
__device__ __forceinline__ float waveMax(float v){
#pragma unroll
  for (int o = 32; o; o >>= 1) v = fmaxf(v, __shfl_xor(v, o, 64));
  return v;
}

// ---------------- Kernel 1: per-row softmax stats, tp, new_target -------------
__global__ __launch_bounds__(256) void k1_softmax_tp(
    const float* __restrict__ outputs, const float* __restrict__ Y,
    float* __restrict__ nt, int* __restrict__ tp)
{
  const int i = blockIdx.x;                 // 0..B_-1
  const float* o = outputs + (size_t)i * C_;
  const float* y = Y + (size_t)i * C_;
  const int t = threadIdx.x;
  __shared__ float sm[4], ss[4], sv[4];
  __shared__ int   si[4];

  float m = -3.4e38f;
  for (int c = t; c < C_; c += 256) m = fmaxf(m, o[c]);
  m = waveMax(m);
  if ((t & 63) == 0) sm[t >> 6] = m;
  __syncthreads();
  m = fmaxf(fmaxf(sm[0], sm[1]), fmaxf(sm[2], sm[3]));

  float s = 0.f; float bv = -3.4e38f; int bi = 0x7fffffff;
  for (int c = t; c < C_; c += 256){
    float oc = o[c];
    if (y[c] > 0.f){
      s += __expf(oc - m);
      if (oc > bv || (oc == bv && c < bi)){ bv = oc; bi = c; }
    }
  }
  s = waveSum(s);
#pragma unroll
  for (int off = 32; off; off >>= 1){
    float ov = __shfl_xor(bv, off, 64);
    int   oi = __shfl_xor(bi, off, 64);
    if (ov > bv || (ov == bv && oi < bi)){ bv = ov; bi = oi; }
  }
  if ((t & 63) == 0){ ss[t >> 6] = s; sv[t >> 6] = bv; si[t >> 6] = bi; }
  __syncthreads();
  s = ss[0] + ss[1] + ss[2] + ss[3];
  bv = sv[0]; bi = si[0];
#pragma unroll
  for (int w = 1; w < 4; ++w)
    if (sv[w] > bv || (sv[w] == bv && si[w] < bi)){ bv = sv[w]; bi = si[w]; }

  const float inv = 1.f / s;
  for (int c = t; c < C_; c += 256)
    nt[(size_t)i * C_ + c] = (y[c] > 0.f) ? __expf(o[c] - m) * inv : 0.f;

  if (t == 0){
    if (bi < 0 || bi >= C_) bi = 0;
    tp[i] = bi;
  }
}

// ---------------- Kernel 1b: counts histogram -> per-j count (single block) ---
__global__ __launch_bounds__(256) void k1b_counts(
    const int* __restrict__ tp, int* __restrict__ cj)
{
  __shared__ int h[C_];
  for (int c = threadIdx.x; c < C_; c += 256) h[c] = 0;
  __syncthreads();
  for (int j = threadIdx.x; j < B_; j += 256) atomicAdd(&h[tp[j]], 1);
  __syncthreads();
  for (int j = threadIdx.x; j < B_; j += 256) cj[j] = h[tp[j]];
}

// ---------------- Kernel 3: maskB (B x B) + row sums + cf->bf16 convert -------
__global__ __launch_bounds__(256) void k3_mask(
    const float* __restrict__ Y, const float* __restrict__ ps,
    const int* __restrict__ tp, const int* __restrict__ cj,
    const float* __restrict__ feat, unsigned short* __restrict__ cfb,
    float* __restrict__ maskB, float* __restrict__ rowsum)
{
  const int i = blockIdx.x;                  // 0..B_-1
  // fold former k2: this block converts flat cfb elements [i*512, i*512+512)
#pragma unroll
  for (int rep = 0; rep < 2; ++rep){
    int idx = i * 512 + rep * 256 + threadIdx.x;
    int r = idx >> 8, d = idx & 255;
    int src = (r < B_) ? (r * 512 + d) : ((r - B_) * 512 + 256 + d);
    uint32_t u = __float_as_uint(feat[src]);
    u += 0x7fffu + ((u >> 16) & 1u);         // RNE to bf16
    cfb[idx] = (unsigned short)(u >> 16);
  }

  const float* y = Y + (size_t)i * C_;
  const float* p = ps + (size_t)i * C_;
  float loc = 0.f;
  for (int j = threadIdx.x; j < B_; j += 256){
    int tj = tp[j];
    float v = y[tj] * p[tj] / (float)cj[j];
    maskB[(size_t)i * B_ + j] = v;
    loc += v;
  }
  loc = waveSum(loc);
  __shared__ float sr[4];
  if ((threadIdx.x & 63) == 0) sr[threadIdx.x >> 6] = loc;
  __syncthreads();
  if (threadIdx.x == 0) rowsum[i] = sr[0] + sr[1] + sr[2] + sr[3];
}

// ---------------- Kernel 4: fused bf16 MFMA GEMM + row reductions -------------
// grid (N2/64, JSPLIT), 256 threads (4 waves). Each wave owns 16 "i" columns
// (MFMA n-axis), iterates the block's j-range (MFMA m-axis) in 64-row LDS chunks.
__global__ __launch_bounds__(256) void k4_gemm(
    const unsigned short* __restrict__ cfb, const float* __restrict__ maskB,
    float* __restrict__ gE, float* __restrict__ gS1)
{
  __shared__ uint4 lds4[2048];               // 64 rows x 512 B = 32 KiB
  const int tid = threadIdx.x;
  const int w = tid >> 6;
  const int l = tid & 63;
  const int Ib = blockIdx.x * 64;
  const int Jb = blockIdx.y * (N2 / JSPLIT);
  const int irow = Ib + w * 16 + (l & 15);
  const int ip = irow & (B_ - 1);

  // B-operand fragments: rows i of cf, k-chunk (l>>4)*8, held for whole kernel
  short8 bfrag[8];
#pragma unroll
  for (int kk = 0; kk < 8; ++kk)
    bfrag[kk] = *reinterpret_cast<const short8*>(
        cfb + ((size_t)irow << 8) + (kk << 5) + ((l >> 4) << 3));

  float E = 0.f, S1 = 0.f;

  for (int ch = 0; ch < (N2 / JSPLIT) / 64; ++ch){
    const int Jc = Jb + ch * 64;
    __syncthreads();
    // stage 64 j-rows, XOR-swizzled (byte ^= (row&7)<<4), linear LDS dest
#pragma unroll
    for (int rep = 0; rep < 8; ++rep){
      int q    = tid + (rep << 8);
      int rowl = q >> 5;
      int c16  = (q & 31) ^ (rowl & 7);      // pre-swizzled source slot
      lds4[q] = *reinterpret_cast<const uint4*>(
          cfb + ((size_t)(Jc + rowl) << 8) + (c16 << 3));
    }
    __syncthreads();

#pragma unroll
    for (int s = 0; s < 4; ++s){
      f32x4 acc = {0.f, 0.f, 0.f, 0.f};
      const int arow = s * 16 + (l & 15);
#pragma unroll
      for (int kk = 0; kk < 8; ++kk){
        int idx16 = arow * 32 + ((kk * 4 + (l >> 4)) ^ (l & 7));
        short8 af = *reinterpret_cast<const short8*>(&lds4[idx16]);
        acc = __builtin_amdgcn_mfma_f32_16x16x32_bf16(af, bfrag[kk], acc, 0, 0, 0);
      }
      // epilogue: lane holds D[m][n], m=j=(l>>4)*4+r (4 consecutive), n=i=l&15
      const int jg0 = Jc + s * 16 + ((l >> 4) << 2);
      const int jp  = jg0 & (B_ - 1);
      const float4 mq = *reinterpret_cast<const float4*>(maskB + (size_t)ip * B_ + jp);
      const float mv[4] = {mq.x, mq.y, mq.z, mq.w};
#pragma unroll
      for (int r = 0; r < 4; ++r){
        float d = acc[r] * 10.f;             // adc = dot / T
        if (jg0 + r != irow){                // skip exact diagonal
          E  += __expf(d - 10.f);            // M = 10 (row max = diagonal)
          S1 += mv[r] * d;
        }
      }
    }
  }
  // combine lanes sharing the same i (l, l+16, l+32, l+48)
  E  += __shfl_xor(E, 16, 64);  E  += __shfl_xor(E, 32, 64);
  S1 += __shfl_xor(S1, 16, 64); S1 += __shfl_xor(S1, 32, 64);
  if ((l >> 4) == 0){
    gE [(size_t)blockIdx.y * N2 + irow] = E;   // unique writer per (split,row)
    gS1[(size_t)blockIdx.y * N2 + irow] = S1;
  }
}

// ---------------- Kernel 5: final loss reduction -------------------------------
__global__ __launch_bounds__(256) void k5_final(
    const float* __restrict__ gE, const float* __restrict__ gS1,
    const float* __restrict__ rowsum, const float* __restrict__ maskB,
    float* __restrict__ out)
{
  float loc = 0.f;
  for (int i = threadIdx.x; i < N2; i += 256){
    int ipp = i & (B_ - 1);
    float E = 0.f, S1 = 0.f;
#pragma unroll
    for (int p = 0; p < JSPLIT; ++p){
      E  += gE [(size_t)p * N2 + i];
      S1 += gS1[(size_t)p * N2 + i];
    }
    float msum = 2.f * rowsum[ipp] - maskB[(size_t)ipp * B_ + ipp];
    // contrib = S1 - msum*M - msum*log(E) with M=10
    loc += S1 - msum * (10.f + logf(E));
  }
  loc = waveSum(loc);
  __shared__ float sr[4];
  if ((threadIdx.x & 63) == 0) sr[threadIdx.x >> 6] = loc;
  __syncthreads();
  if (threadIdx.x == 0){
    float tot = sr[0] + sr[1] + sr[2] + sr[3];
    out[0] = -(0.1f / 0.07f) * (tot / (float)N2);
  }
}

// ---------------- launch -------------------------------------------------------
extern "C" void kernel_launch(void* const* d_in, const int* in_sizes, int n_in,
                              void* d_out, int out_size, void* d_ws, size_t ws_size,
                              hipStream_t stream)
{
  const float* outputs  = (const float*)d_in[0];   // (2B, C) f32
  const float* features = (const float*)d_in[1];   // (B, 2, D) f32 (normalized)
  const float* Y        = (const float*)d_in[2];   // (B, C) f32
  const float* ps       = (const float*)d_in[3];   // (B, C) f32
  float* out = (float*)d_out;                      // [loss, new_target(B*C)]

  char* ws = (char*)d_ws;
  int*   tp     = (int*)(ws);                      // 2048 ints   @ 0
  int*   cj     = (int*)(ws + 8192);               // 2048 ints   @ 8192
  float* rowsum = (float*)(ws + 16384);            // 2048 f32    @ 16384
  float* gE     = (float*)(ws + 24576);            // 8*4096 f32  @ 24576
  float* gS1    = (float*)(ws + 155648);           // 8*4096 f32  @ 155648
  unsigned short* cfb = (unsigned short*)(ws + 286720);  // 4096*256 bf16 (2 MiB)
  float* maskB  = (float*)(ws + 2383872);          // 2048*2048 f32 (16 MiB)

  k1_softmax_tp<<<B_, 256, 0, stream>>>(outputs, Y, out + 1, tp);
  k1b_counts<<<1, 256, 0, stream>>>(tp, cj);
  k3_mask<<<B_, 256, 0, stream>>>(Y, ps, tp, cj, features, cfb, maskB, rowsum);
  k4_gemm<<<dim3(N2 / 64, JSPLIT), 256, 0, stream>>>(cfb, maskB, gE, gS1);
  k5_final<<<1, 256, 0, stream>>>(gE, gS1, rowsum, maskB, out);
}

// Round 3
// 69.613 us; speedup vs baseline: 1.2248x; 1.2248x over previous
//
#include <hip/hip_runtime.h>
#include <stdint.h>

#define B_   2048
#define C_   1000
#define N2   4096
#define D_   256
#define JSPLIT 16
#define IBLK   128                 // i-rows per k4 block (8 waves x 16)
#define NCH    ((N2 / JSPLIT) / 64)  // 4 chunks of 64 j-rows

typedef float  f32x4  __attribute__((ext_vector_type(4)));
typedef short  short8 __attribute__((ext_vector_type(8)));

__device__ __forceinline__ float waveSum(float v){
#pragma unroll
  for (int o = 32; o; o >>= 1) v += __shfl_xor(v, o, 64);
  return v;
}
__device__ __forceinline__ float waveMax(float v){
#pragma unroll
  for (int o = 32; o; o >>= 1) v = fmaxf(v, __shfl_xor(v, o, 64));
  return v;
}

// ---- Kernel 1: wave-per-row softmax + tp + new_target (single global pass) ---
__global__ __launch_bounds__(256) void k1_softmax_tp(
    const float* __restrict__ outputs, const float* __restrict__ Y,
    float* __restrict__ nt, int* __restrict__ tp)
{
  const int w = threadIdx.x >> 6, l = threadIdx.x & 63;
  const int i = blockIdx.x * 4 + w;                    // 0..B_-1
  const float4* o4 = (const float4*)(outputs + (size_t)i * C_);  // 1000%4==0: aligned
  const float4* y4 = (const float4*)(Y + (size_t)i * C_);

  float4 ov[4], yv[4];
#pragma unroll
  for (int q = 0; q < 4; ++q){
    int idx = q * 64 + l;
    if (idx < 250){ ov[q] = o4[idx]; yv[q] = y4[idx]; }
    else { ov[q] = make_float4(-3.4e38f,-3.4e38f,-3.4e38f,-3.4e38f);
           yv[q] = make_float4(0.f,0.f,0.f,0.f); }
  }

  float m = -3.4e38f;
#pragma unroll
  for (int q = 0; q < 4; ++q)
    m = fmaxf(m, fmaxf(fmaxf(ov[q].x, ov[q].y), fmaxf(ov[q].z, ov[q].w)));
  m = waveMax(m);

  float s = 0.f, bv = -3.4e38f; int bi = 0x7fffffff;
#pragma unroll
  for (int q = 0; q < 4; ++q){
    int c0 = (q * 64 + l) * 4;
    const float* op = (const float*)&ov[q];
    const float* yp = (const float*)&yv[q];
#pragma unroll
    for (int r = 0; r < 4; ++r){
      if (yp[r] > 0.f){
        float oc = op[r];
        s += __expf(oc - m);
        if (oc > bv || (oc == bv && c0 + r < bi)){ bv = oc; bi = c0 + r; }
      }
    }
  }
  s = waveSum(s);
#pragma unroll
  for (int off = 32; off; off >>= 1){
    float ovv = __shfl_xor(bv, off, 64);
    int   oii = __shfl_xor(bi, off, 64);
    if (ovv > bv || (ovv == bv && oii < bi)){ bv = ovv; bi = oii; }
  }

  const float inv = 1.f / s;
  float* ntp = nt + (size_t)i * C_;                    // 4B-aligned only: scalar stores
#pragma unroll
  for (int q = 0; q < 4; ++q){
    int idx = q * 64 + l;
    if (idx < 250){
      int c0 = idx * 4;
      const float* op = (const float*)&ov[q];
      const float* yp = (const float*)&yv[q];
#pragma unroll
      for (int r = 0; r < 4; ++r)
        ntp[c0 + r] = (yp[r] > 0.f) ? __expf(op[r] - m) * inv : 0.f;
    }
  }
  if (l == 0){
    if (bi < 0 || bi >= C_) bi = 0;
    tp[i] = bi;
  }
}

// ---- Kernel 3: maskB + rowsum + cf->bf16; per-block redundant tp-histogram ---
__global__ __launch_bounds__(256) void k3_mask(
    const float* __restrict__ Y, const float* __restrict__ ps,
    const int* __restrict__ tp,
    const float* __restrict__ feat, unsigned short* __restrict__ cfb,
    float* __restrict__ maskB, float* __restrict__ rowsum)
{
  __shared__ int h[C_];
  const int i = blockIdx.x, t = threadIdx.x;

  // fold: convert flat cfb elements [i*512, i*512+512)
#pragma unroll
  for (int rep = 0; rep < 2; ++rep){
    int idx = i * 512 + rep * 256 + t;
    int r = idx >> 8, d = idx & 255;
    int src = (r < B_) ? (r * 512 + d) : ((r - B_) * 512 + 256 + d);
    uint32_t u = __float_as_uint(feat[src]);
    u += 0x7fffu + ((u >> 16) & 1u);         // RNE to bf16
    cfb[idx] = (unsigned short)(u >> 16);
  }

  for (int c = t; c < C_; c += 256) h[c] = 0;
  __syncthreads();
  const int4 t0 = ((const int4*)tp)[t];          // j = 4t .. 4t+3
  const int4 t1 = ((const int4*)tp)[t + 256];    // j = 1024+4t ..
  atomicAdd(&h[t0.x], 1); atomicAdd(&h[t0.y], 1);
  atomicAdd(&h[t0.z], 1); atomicAdd(&h[t0.w], 1);
  atomicAdd(&h[t1.x], 1); atomicAdd(&h[t1.y], 1);
  atomicAdd(&h[t1.z], 1); atomicAdd(&h[t1.w], 1);
  __syncthreads();

  const float* y = Y + (size_t)i * C_;
  const float* p = ps + (size_t)i * C_;
  float4 v0, v1;
  v0.x = y[t0.x] * p[t0.x] / (float)h[t0.x];
  v0.y = y[t0.y] * p[t0.y] / (float)h[t0.y];
  v0.z = y[t0.z] * p[t0.z] / (float)h[t0.z];
  v0.w = y[t0.w] * p[t0.w] / (float)h[t0.w];
  v1.x = y[t1.x] * p[t1.x] / (float)h[t1.x];
  v1.y = y[t1.y] * p[t1.y] / (float)h[t1.y];
  v1.z = y[t1.z] * p[t1.z] / (float)h[t1.z];
  v1.w = y[t1.w] * p[t1.w] / (float)h[t1.w];
  ((float4*)(maskB + (size_t)i * B_))[t]       = v0;
  ((float4*)(maskB + (size_t)i * B_))[t + 256] = v1;

  float loc = (v0.x + v0.y + v0.z + v0.w) + (v1.x + v1.y + v1.z + v1.w);
  loc = waveSum(loc);
  __shared__ float sr[4];
  if ((t & 63) == 0) sr[t >> 6] = loc;
  __syncthreads();
  if (t == 0) rowsum[i] = sr[0] + sr[1] + sr[2] + sr[3];
}

// ---- Kernel 4: fused bf16 MFMA GEMM + row reductions -------------------------
// grid (N2/IBLK, JSPLIT), 512 threads (8 waves). Wave w owns i-rows
// Ib+w*16..+15 (MFMA n-axis); block iterates its j-range in 64-row LDS chunks
// with async-stage (regs) overlap of the next chunk under compute.
__global__ __launch_bounds__(512, 4) void k4_gemm(
    const unsigned short* __restrict__ cfb, const float* __restrict__ maskB,
    float* __restrict__ gE, float* __restrict__ gS1)
{
  __shared__ uint4 lds4[2048];               // 64 rows x 512 B = 32 KiB
  const int tid = threadIdx.x;
  const int w = tid >> 6;
  const int l = tid & 63;
  const int Ib = blockIdx.x * IBLK;
  const int Jb = blockIdx.y * (N2 / JSPLIT);
  const int irow = Ib + w * 16 + (l & 15);
  const int ip = irow & (B_ - 1);

  short8 bfrag[8];
#pragma unroll
  for (int kk = 0; kk < 8; ++kk)
    bfrag[kk] = *reinterpret_cast<const short8*>(
        cfb + ((size_t)irow << 8) + (kk << 5) + ((l >> 4) << 3));

  uint4 st[4];                               // staging regs: 64B/thread
#define LOADC(JC)                                                        \
  { _Pragma("unroll")                                                    \
    for (int rep = 0; rep < 4; ++rep){                                   \
      int q = tid + (rep << 9);                                          \
      int rowl = q >> 5;                                                 \
      int c16 = (q & 31) ^ (rowl & 7);     /* pre-swizzled source */     \
      st[rep] = *reinterpret_cast<const uint4*>(                         \
          cfb + ((size_t)((JC) + rowl) << 8) + (c16 << 3));              \
    } }
#define WRITEC()                                                         \
  { _Pragma("unroll")                                                    \
    for (int rep = 0; rep < 4; ++rep) lds4[tid + (rep << 9)] = st[rep]; }

  float E = 0.f, S1 = 0.f;
  LOADC(Jb);
  WRITEC();
  __syncthreads();

  for (int ch = 0; ch < NCH; ++ch){
    const int Jc = Jb + ch * 64;
    if (ch + 1 < NCH) LOADC(Jc + 64);        // in flight under compute

#pragma unroll
    for (int s = 0; s < 4; ++s){
      f32x4 acc = {0.f, 0.f, 0.f, 0.f};
      const int arow = s * 16 + (l & 15);
#pragma unroll
      for (int kk = 0; kk < 8; ++kk){
        int idx16 = arow * 32 + ((kk * 4 + (l >> 4)) ^ (l & 7));
        short8 af = *reinterpret_cast<const short8*>(&lds4[idx16]);
        acc = __builtin_amdgcn_mfma_f32_16x16x32_bf16(af, bfrag[kk], acc, 0, 0, 0);
      }
      const int jg0 = Jc + s * 16 + ((l >> 4) << 2);
      const int jp  = jg0 & (B_ - 1);
      const float4 mq = *reinterpret_cast<const float4*>(maskB + (size_t)ip * B_ + jp);
      const float mv[4] = {mq.x, mq.y, mq.z, mq.w};
#pragma unroll
      for (int r = 0; r < 4; ++r){
        float d = acc[r] * 10.f;             // adc = dot / T
        if (jg0 + r != irow){                // skip exact diagonal
          E  += __expf(d - 10.f);            // M = 10 (row max = diagonal)
          S1 += mv[r] * d;
        }
      }
    }
    __syncthreads();                         // all waves done reading lds4
    if (ch + 1 < NCH){ WRITEC(); }
    __syncthreads();
  }

  E  += __shfl_xor(E, 16, 64);  E  += __shfl_xor(E, 32, 64);
  S1 += __shfl_xor(S1, 16, 64); S1 += __shfl_xor(S1, 32, 64);
  if ((l >> 4) == 0){
    gE [(size_t)blockIdx.y * N2 + irow] = E;   // unique writer per (split,row)
    gS1[(size_t)blockIdx.y * N2 + irow] = S1;
  }
#undef LOADC
#undef WRITEC
}

// ---- Kernel 5: final loss reduction ------------------------------------------
__global__ __launch_bounds__(1024) void k5_final(
    const float* __restrict__ gE, const float* __restrict__ gS1,
    const float* __restrict__ rowsum, const float* __restrict__ maskB,
    float* __restrict__ out)
{
  float loc = 0.f;
  for (int i = threadIdx.x; i < N2; i += 1024){
    int ipp = i & (B_ - 1);
    float E = 0.f, S1 = 0.f;
#pragma unroll
    for (int p = 0; p < JSPLIT; ++p){
      E  += gE [(size_t)p * N2 + i];
      S1 += gS1[(size_t)p * N2 + i];
    }
    float msum = 2.f * rowsum[ipp] - maskB[(size_t)ipp * B_ + ipp];
    loc += S1 - msum * (10.f + logf(E));     // contrib with M=10
  }
  loc = waveSum(loc);
  __shared__ float sr[16];
  if ((threadIdx.x & 63) == 0) sr[threadIdx.x >> 6] = loc;
  __syncthreads();
  if (threadIdx.x == 0){
    float tot = 0.f;
#pragma unroll
    for (int q = 0; q < 16; ++q) tot += sr[q];
    out[0] = -(0.1f / 0.07f) * (tot / (float)N2);
  }
}

// ---- launch ------------------------------------------------------------------
extern "C" void kernel_launch(void* const* d_in, const int* in_sizes, int n_in,
                              void* d_out, int out_size, void* d_ws, size_t ws_size,
                              hipStream_t stream)
{
  const float* outputs  = (const float*)d_in[0];   // (2B, C) f32
  const float* features = (const float*)d_in[1];   // (B, 2, D) f32 (normalized)
  const float* Y        = (const float*)d_in[2];   // (B, C) f32
  const float* ps       = (const float*)d_in[3];   // (B, C) f32
  float* out = (float*)d_out;                      // [loss, new_target(B*C)]

  char* ws = (char*)d_ws;
  int*   tp     = (int*)(ws);                      // 2048 ints        @ 0
  float* rowsum = (float*)(ws + 8192);             // 2048 f32         @ 8192
  float* gE     = (float*)(ws + 16384);            // 16*4096 f32      @ 16384
  float* gS1    = (float*)(ws + 278528);           // 16*4096 f32      @ 278528
  unsigned short* cfb = (unsigned short*)(ws + 540672);  // 4096*256 bf16 (2 MiB)
  float* maskB  = (float*)(ws + 2637824);          // 2048*2048 f32 (16 MiB)

  k1_softmax_tp<<<B_ / 4, 256, 0, stream>>>(outputs, Y, out + 1, tp);
  k3_mask<<<B_, 256, 0, stream>>>(Y, ps, tp, features, cfb, maskB, rowsum);
  k4_gemm<<<dim3(N2 / IBLK, JSPLIT), 512, 0, stream>>>(cfb, maskB, gE, gS1);
  k5_final<<<1, 1024, 0, stream>>>(gE, gS1, rowsum, maskB, out);
}

// Round 4
// 68.315 us; speedup vs baseline: 1.2481x; 1.0190x over previous
//
#include <hip/hip_runtime.h>
#include <stdint.h>

#define B_   2048
#define C_   1000
#define N2   4096
#define D_   256
#define JSPLIT 16
#define IBLK   128                   // i-rows per k4 block (8 waves x 16)
#define NCH    ((N2 / JSPLIT) / 64)  // 4 chunks of 64 j-rows

typedef float  f32x4  __attribute__((ext_vector_type(4)));
typedef short  short8 __attribute__((ext_vector_type(8)));

__device__ __forceinline__ float waveSum(float v){
#pragma unroll
  for (int o = 32; o; o >>= 1) v += __shfl_xor(v, o, 64);
  return v;
}
__device__ __forceinline__ float waveMax(float v){
#pragma unroll
  for (int o = 32; o; o >>= 1) v = fmaxf(v, __shfl_xor(v, o, 64));
  return v;
}
__device__ __forceinline__ unsigned short f2bf(float f){
  uint32_t u = __float_as_uint(f);
  u += 0x7fffu + ((u >> 16) & 1u);           // RNE
  return (unsigned short)(u >> 16);
}
__device__ __forceinline__ float bf2f(unsigned short h){
  return __uint_as_float(((uint32_t)h) << 16);
}

// ---- Kernel 1: wave-per-row softmax + tp + new_target (single global pass) ---
__global__ __launch_bounds__(256) void k1_softmax_tp(
    const float* __restrict__ outputs, const float* __restrict__ Y,
    float* __restrict__ nt, int* __restrict__ tp)
{
  const int w = threadIdx.x >> 6, l = threadIdx.x & 63;
  const int i = blockIdx.x * 4 + w;                    // 0..B_-1
  const float4* o4 = (const float4*)(outputs + (size_t)i * C_);
  const float4* y4 = (const float4*)(Y + (size_t)i * C_);

  float4 ov[4], yv[4];
#pragma unroll
  for (int q = 0; q < 4; ++q){
    int idx = q * 64 + l;
    if (idx < 250){ ov[q] = o4[idx]; yv[q] = y4[idx]; }
    else { ov[q] = make_float4(-3.4e38f,-3.4e38f,-3.4e38f,-3.4e38f);
           yv[q] = make_float4(0.f,0.f,0.f,0.f); }
  }

  float m = -3.4e38f;
#pragma unroll
  for (int q = 0; q < 4; ++q)
    m = fmaxf(m, fmaxf(fmaxf(ov[q].x, ov[q].y), fmaxf(ov[q].z, ov[q].w)));
  m = waveMax(m);

  float s = 0.f, bv = -3.4e38f; int bi = 0x7fffffff;
#pragma unroll
  for (int q = 0; q < 4; ++q){
    int c0 = (q * 64 + l) * 4;
    const float* op = (const float*)&ov[q];
    const float* yp = (const float*)&yv[q];
#pragma unroll
    for (int r = 0; r < 4; ++r){
      if (yp[r] > 0.f){
        float oc = op[r];
        s += __expf(oc - m);
        if (oc > bv || (oc == bv && c0 + r < bi)){ bv = oc; bi = c0 + r; }
      }
    }
  }
  s = waveSum(s);
#pragma unroll
  for (int off = 32; off; off >>= 1){
    float ovv = __shfl_xor(bv, off, 64);
    int   oii = __shfl_xor(bi, off, 64);
    if (ovv > bv || (ovv == bv && oii < bi)){ bv = ovv; bi = oii; }
  }

  const float inv = 1.f / s;
  float* ntp = nt + (size_t)i * C_;          // 4B-aligned only: scalar stores
#pragma unroll
  for (int q = 0; q < 4; ++q){
    int idx = q * 64 + l;
    if (idx < 250){
      int c0 = idx * 4;
      const float* op = (const float*)&ov[q];
      const float* yp = (const float*)&yv[q];
#pragma unroll
      for (int r = 0; r < 4; ++r)
        ntp[c0 + r] = (yp[r] > 0.f) ? __expf(op[r] - m) * inv : 0.f;
    }
  }
  if (l == 0){
    if (bi < 0 || bi >= C_) bi = 0;
    tp[i] = bi;
  }
}

// ---- Kernel 3: maskB (bf16) + rowsum + cf->bf16; per-block tp-histogram ------
__global__ __launch_bounds__(256) void k3_mask(
    const float* __restrict__ Y, const float* __restrict__ ps,
    const int* __restrict__ tp,
    const float* __restrict__ feat, unsigned short* __restrict__ cfb,
    unsigned short* __restrict__ maskB, float* __restrict__ rowsum)
{
  __shared__ int h[C_];
  const int i = blockIdx.x, t = threadIdx.x;

  // fold: convert flat cfb elements [i*512, i*512+512)
#pragma unroll
  for (int rep = 0; rep < 2; ++rep){
    int idx = i * 512 + rep * 256 + t;
    int r = idx >> 8, d = idx & 255;
    int src = (r < B_) ? (r * 512 + d) : ((r - B_) * 512 + 256 + d);
    cfb[idx] = f2bf(feat[src]);
  }

  for (int c = t; c < C_; c += 256) h[c] = 0;
  __syncthreads();
  const int4 t0 = ((const int4*)tp)[t];          // j = 4t .. 4t+3
  const int4 t1 = ((const int4*)tp)[t + 256];    // j = 1024+4t ..
  atomicAdd(&h[t0.x], 1); atomicAdd(&h[t0.y], 1);
  atomicAdd(&h[t0.z], 1); atomicAdd(&h[t0.w], 1);
  atomicAdd(&h[t1.x], 1); atomicAdd(&h[t1.y], 1);
  atomicAdd(&h[t1.z], 1); atomicAdd(&h[t1.w], 1);
  __syncthreads();

  const float* y = Y + (size_t)i * C_;
  const float* p = ps + (size_t)i * C_;
  float v0[4], v1[4];
  v0[0] = y[t0.x] * p[t0.x] / (float)h[t0.x];
  v0[1] = y[t0.y] * p[t0.y] / (float)h[t0.y];
  v0[2] = y[t0.z] * p[t0.z] / (float)h[t0.z];
  v0[3] = y[t0.w] * p[t0.w] / (float)h[t0.w];
  v1[0] = y[t1.x] * p[t1.x] / (float)h[t1.x];
  v1[1] = y[t1.y] * p[t1.y] / (float)h[t1.y];
  v1[2] = y[t1.z] * p[t1.z] / (float)h[t1.z];
  v1[3] = y[t1.w] * p[t1.w] / (float)h[t1.w];

  uint2 pk0, pk1;
  pk0.x = (uint32_t)f2bf(v0[0]) | ((uint32_t)f2bf(v0[1]) << 16);
  pk0.y = (uint32_t)f2bf(v0[2]) | ((uint32_t)f2bf(v0[3]) << 16);
  pk1.x = (uint32_t)f2bf(v1[0]) | ((uint32_t)f2bf(v1[1]) << 16);
  pk1.y = (uint32_t)f2bf(v1[2]) | ((uint32_t)f2bf(v1[3]) << 16);
  ((uint2*)(maskB + (size_t)i * B_))[t]       = pk0;
  ((uint2*)(maskB + (size_t)i * B_))[t + 256] = pk1;

  float loc = (v0[0] + v0[1] + v0[2] + v0[3]) + (v1[0] + v1[1] + v1[2] + v1[3]);
  loc = waveSum(loc);
  __shared__ float sr[4];
  if ((t & 63) == 0) sr[t >> 6] = loc;
  __syncthreads();
  if (t == 0) rowsum[i] = sr[0] + sr[1] + sr[2] + sr[3];
}

// ---- Kernel 4: fused bf16 MFMA GEMM + row reductions -------------------------
// grid (N2/IBLK, JSPLIT), 512 threads (8 waves). A-operand = wave's 16 i-rows
// (registers), B-operand = 64-j-row LDS chunks. D: col = j (l&15, contiguous),
// row = i ((l>>4)*4+r) -> coalesced bf16 mask reads.
__global__ __launch_bounds__(512, 4) void k4_gemm(
    const unsigned short* __restrict__ cfb, const unsigned short* __restrict__ maskB,
    float* __restrict__ gE, float* __restrict__ gS1)
{
  __shared__ uint4 lds4[2048];               // 64 rows x 512 B = 32 KiB
  const int tid = threadIdx.x;
  const int w = tid >> 6;
  const int l = tid & 63;
  const int Ib = blockIdx.x * IBLK;
  const int Jb = blockIdx.y * (N2 / JSPLIT);
  const int iA = Ib + w * 16 + (l & 15);     // A-fragment row this lane loads
  const int irow0 = Ib + w * 16 + ((l >> 4) << 2);  // first output i-row (D)

  short8 afrag[8];
#pragma unroll
  for (int kk = 0; kk < 8; ++kk)
    afrag[kk] = *reinterpret_cast<const short8*>(
        cfb + ((size_t)iA << 8) + (kk << 5) + ((l >> 4) << 3));

  uint4 st[4];                               // staging regs: 64B/thread
#define LOADC(JC)                                                        \
  { _Pragma("unroll")                                                    \
    for (int rep = 0; rep < 4; ++rep){                                   \
      int q = tid + (rep << 9);                                          \
      int rowl = q >> 5;                                                 \
      int c16 = (q & 31) ^ (rowl & 7);     /* pre-swizzled source */     \
      st[rep] = *reinterpret_cast<const uint4*>(                         \
          cfb + ((size_t)((JC) + rowl) << 8) + (c16 << 3));              \
    } }
#define WRITEC()                                                         \
  { _Pragma("unroll")                                                    \
    for (int rep = 0; rep < 4; ++rep) lds4[tid + (rep << 9)] = st[rep]; }

  float E[4]  = {0.f, 0.f, 0.f, 0.f};
  float S1[4] = {0.f, 0.f, 0.f, 0.f};
  LOADC(Jb);
  WRITEC();
  __syncthreads();

  for (int ch = 0; ch < NCH; ++ch){
    const int Jc = Jb + ch * 64;
    if (ch + 1 < NCH) LOADC(Jc + 64);        // in flight under compute

#pragma unroll
    for (int s = 0; s < 4; ++s){
      f32x4 acc = {0.f, 0.f, 0.f, 0.f};
      const int brow = s * 16 + (l & 15);    // j-row of LDS tile (B operand)
#pragma unroll
      for (int kk = 0; kk < 8; ++kk){
        int idx16 = brow * 32 + ((kk * 4 + (l >> 4)) ^ (l & 7));
        short8 bfr = *reinterpret_cast<const short8*>(&lds4[idx16]);
        acc = __builtin_amdgcn_mfma_f32_16x16x32_bf16(afrag[kk], bfr, acc, 0, 0, 0);
      }
      const int j  = Jc + s * 16 + (l & 15);
      const int jp = j & (B_ - 1);
#pragma unroll
      for (int r = 0; r < 4; ++r){
        const int ir  = irow0 + r;
        const int ipr = ir & (B_ - 1);
        float mv = bf2f(maskB[(size_t)ipr * B_ + jp]);   // coalesced over l&15
        float d = acc[r] * 10.f;             // adc = dot / T
        if (j != ir){                        // skip exact diagonal
          E[r]  += __expf(d - 10.f);         // M = 10 (row max = diagonal)
          S1[r] += mv * d;
        }
      }
    }
    __syncthreads();                         // all waves done reading lds4
    if (ch + 1 < NCH){ WRITEC(); }
    __syncthreads();
  }

  // reduce across the 16 lanes of each quadrant (same output i-row set)
#pragma unroll
  for (int r = 0; r < 4; ++r){
    float e = E[r], s1 = S1[r];
#pragma unroll
    for (int off = 1; off < 16; off <<= 1){
      e  += __shfl_xor(e,  off, 64);
      s1 += __shfl_xor(s1, off, 64);
    }
    if ((l & 15) == 0){
      gE [(size_t)blockIdx.y * N2 + irow0 + r] = e;   // unique writer
      gS1[(size_t)blockIdx.y * N2 + irow0 + r] = s1;
    }
  }
#undef LOADC
#undef WRITEC
}

// ---- Kernel 5: final loss reduction ------------------------------------------
__global__ __launch_bounds__(1024) void k5_final(
    const float* __restrict__ gE, const float* __restrict__ gS1,
    const float* __restrict__ rowsum, const unsigned short* __restrict__ maskB,
    float* __restrict__ out)
{
  float loc = 0.f;
  for (int i = threadIdx.x; i < N2; i += 1024){
    int ipp = i & (B_ - 1);
    float E = 0.f, S1 = 0.f;
#pragma unroll
    for (int p = 0; p < JSPLIT; ++p){
      E  += gE [(size_t)p * N2 + i];
      S1 += gS1[(size_t)p * N2 + i];
    }
    float msum = 2.f * rowsum[ipp] - bf2f(maskB[(size_t)ipp * B_ + ipp]);
    loc += S1 - msum * (10.f + logf(E));     // contrib with M=10
  }
  loc = waveSum(loc);
  __shared__ float sr[16];
  if ((threadIdx.x & 63) == 0) sr[threadIdx.x >> 6] = loc;
  __syncthreads();
  if (threadIdx.x == 0){
    float tot = 0.f;
#pragma unroll
    for (int q = 0; q < 16; ++q) tot += sr[q];
    out[0] = -(0.1f / 0.07f) * (tot / (float)N2);
  }
}

// ---- launch ------------------------------------------------------------------
extern "C" void kernel_launch(void* const* d_in, const int* in_sizes, int n_in,
                              void* d_out, int out_size, void* d_ws, size_t ws_size,
                              hipStream_t stream)
{
  const float* outputs  = (const float*)d_in[0];   // (2B, C) f32
  const float* features = (const float*)d_in[1];   // (B, 2, D) f32 (normalized)
  const float* Y        = (const float*)d_in[2];   // (B, C) f32
  const float* ps       = (const float*)d_in[3];   // (B, C) f32
  float* out = (float*)d_out;                      // [loss, new_target(B*C)]

  char* ws = (char*)d_ws;
  int*   tp     = (int*)(ws);                      // 2048 ints        @ 0
  float* rowsum = (float*)(ws + 8192);             // 2048 f32         @ 8192
  float* gE     = (float*)(ws + 16384);            // 16*4096 f32      @ 16384
  float* gS1    = (float*)(ws + 278528);           // 16*4096 f32      @ 278528
  unsigned short* cfb   = (unsigned short*)(ws + 540672);   // 4096*256 bf16 (2 MiB)
  unsigned short* maskB = (unsigned short*)(ws + 2637824);  // 2048*2048 bf16 (8 MiB)

  k1_softmax_tp<<<B_ / 4, 256, 0, stream>>>(outputs, Y, out + 1, tp);
  k3_mask<<<B_, 256, 0, stream>>>(Y, ps, tp, features, cfb, maskB, rowsum);
  k4_gemm<<<dim3(N2 / IBLK, JSPLIT), 512, 0, stream>>>(cfb, maskB, gE, gS1);
  k5_final<<<1, 1024, 0, stream>>>(gE, gS1, rowsum, maskB, out);
}